// Round 2
// baseline (738.877 us; speedup 1.0000x reference)
//
#include <hip/hip_runtime.h>
#include <hip/hip_bf16.h>
#include <hip/hip_fp16.h>

#define NB 256      // batch
#define NT 1024     // time
#define ND 64       // input dim
#define NH 128      // hidden dim

typedef __fp16 half8 __attribute__((ext_vector_type(8)));
typedef __fp16 half2v __attribute__((ext_vector_type(2)));
typedef float float4v __attribute__((ext_vector_type(4)));

// fp16 staging layout inside d_out (fp16 elements):
//   gxK[b] at  b*262144 + 131072   (back half of out0's batch-b region)
//   z[b]   at  67108864 + b*262144 + 131072  (back half of out1's batch-b region)
#define REGION_H 262144     // fp16 elems per batch region (= T*H*2)
#define GX_OFF   131072     // fp16 offset of staging inside region (= T*H)
#define Z_BASE   67108864   // fp16 offset of out1 region base (= B*T*H fp32 viewed as fp16 pairs)

static __device__ __forceinline__ float fast_tanh(float v) {
    float e = __expf(2.0f * v);
    return 1.0f - 2.0f * __builtin_amdgcn_rcpf(e + 1.0f);
}

static __device__ __forceinline__ float fdot2f(half2v a, half2v b, float c) {
#if __has_builtin(__builtin_amdgcn_fdot2)
    return __builtin_amdgcn_fdot2(a, b, c, false);
#else
    return c + (float)a.x * (float)b.x + (float)a.y * (float)b.y;
#endif
}

// ---------------- Phase 1: projections via f16 MFMA ----------------
// grid 4096 x 256 threads. Each block: 64 rows of x (BT = 262144 rows).
// gx[m][n] = sum_d x[m][d] * W[n][d]  (einsum btd,hd->bth)
__global__ __launch_bounds__(256) void proj_kernel(
        const float* __restrict__ x,
        const float* __restrict__ WxK, const float* __restrict__ bxK,
        const float* __restrict__ Wxz, const float* __restrict__ bxz,
        __fp16* __restrict__ stg /* = (__fp16*)d_out */) {
    __shared__ __align__(16) __fp16 xsm[64][72];       // +8 pad: 144B stride, 16B aligned, 2-way banks
    __shared__ __align__(16) __fp16 wsm[2][128][72];

    const int tid = threadIdx.x;
    const int m0 = blockIdx.x * 64;

    // stage W (both matrices) as fp16 into LDS
    for (int mat = 0; mat < 2; ++mat) {
        const float* Wsrc = mat ? Wxz : WxK;
        const float4v* ws4 = (const float4v*)(Wsrc + (size_t)(tid >> 1) * 64 + (tid & 1) * 32);
        #pragma unroll
        for (int i = 0; i < 4; ++i) {
            float4v a = ws4[2 * i], b = ws4[2 * i + 1];
            half8 hv = {(__fp16)a.x, (__fp16)a.y, (__fp16)a.z, (__fp16)a.w,
                        (__fp16)b.x, (__fp16)b.y, (__fp16)b.z, (__fp16)b.w};
            *(half8*)&wsm[mat][tid >> 1][(tid & 1) * 32 + i * 8] = hv;
        }
    }
    // stage x tile as fp16
    {
        const float4v* xs4 = (const float4v*)(x + (size_t)(m0 + (tid >> 2)) * 64 + (tid & 3) * 16);
        #pragma unroll
        for (int i = 0; i < 2; ++i) {
            float4v a = xs4[2 * i], b = xs4[2 * i + 1];
            half8 hv = {(__fp16)a.x, (__fp16)a.y, (__fp16)a.z, (__fp16)a.w,
                        (__fp16)b.x, (__fp16)b.y, (__fp16)b.z, (__fp16)b.w};
            *(half8*)&xsm[tid >> 2][(tid & 3) * 16 + i * 8] = hv;
        }
    }
    __syncthreads();

    const int wid = tid >> 6, lane = tid & 63;
    const int l16 = lane & 15, kg = lane >> 4;

    float4v acc[16] = {};   // [nt][mat]
    #pragma unroll
    for (int s = 0; s < 2; ++s) {
        half8 af = *(const half8*)&xsm[wid * 16 + l16][s * 32 + kg * 8];
        #pragma unroll
        for (int nt = 0; nt < 8; ++nt) {
            #pragma unroll
            for (int mat = 0; mat < 2; ++mat) {
                half8 bf = *(const half8*)&wsm[mat][nt * 16 + l16][s * 32 + kg * 8];
                acc[nt * 2 + mat] =
                    __builtin_amdgcn_mfma_f32_16x16x32_f16(af, bf, acc[nt * 2 + mat], 0, 0, 0);
            }
        }
    }

    // epilogue: C/D layout col = lane&15, row = (lane>>4)*4 + r  [m89]
    #pragma unroll
    for (int nt = 0; nt < 8; ++nt) {
        const int col = nt * 16 + l16;
        const float bK = bxK[col], bz = bxz[col];
        #pragma unroll
        for (int r = 0; r < 4; ++r) {
            const int bt = m0 + wid * 16 + kg * 4 + r;
            const int bb = bt >> 10, tt = bt & 1023;
            const size_t base = (size_t)bb * REGION_H + GX_OFF + (size_t)tt * NH + col;
            stg[base] = (__fp16)(acc[nt * 2 + 0][r] + bK);
            stg[base + Z_BASE] = (__fp16)fast_tanh(acc[nt * 2 + 1][r] + bz);
        }
    }
}

// ---------------- Phase 2: sequential recurrence ----------------
// grid 256 (one block = one batch) x 256 threads.
// thread t: j = t>>1 (hidden index), kh = t&1 (k-half). Pair lanes compute
// gate_h[j] cooperatively (shfl_xor(1)), epilogue redundantly on both lanes.
__global__ __launch_bounds__(256) void rnn_kernel(
        const float* __restrict__ Whk, const float* __restrict__ bhk,
        float* __restrict__ out) {
    __shared__ __align__(16) unsigned int hbuf[2][64];        // packed half2 of h, dbuf per step
    __shared__ __align__(16) __fp16 gbuf[2][16][128];         // gxK chunk dbuf (16 steps)
    __shared__ __align__(16) __fp16 zbuf[2][16][128];         // z   chunk dbuf

    const int tid = threadIdx.x;
    const int b = blockIdx.x;
    const int j = tid >> 1, kh = tid & 1;

    // W_hK row j, k-half kh, packed fp16 in 32 VGPRs
    half2v w[32];
    {
        const float4v* wsrc = (const float4v*)(Whk + (size_t)j * NH + kh * 64);
        #pragma unroll
        for (int i = 0; i < 16; ++i) {
            float4v wv = wsrc[i];
            w[2 * i]     = __builtin_amdgcn_cvt_pkrtz(wv.x, wv.y);
            w[2 * i + 1] = __builtin_amdgcn_cvt_pkrtz(wv.z, wv.w);
        }
    }
    const float bj = bhk[j];

    const __fp16* gxb = (const __fp16*)out + (size_t)b * REGION_H + GX_OFF;
    const __fp16* zb  = gxb + (size_t)Z_BASE;
    const float4v* gsrc4 = (const float4v*)gxb;   // 8 fp16 per elem
    const float4v* zsrc4 = (const float4v*)zb;

    // preload chunk 0 straight into LDS buf0
    float4v pg = gsrc4[tid];
    float4v pz = zsrc4[tid];
    ((float4v*)gbuf[0])[tid] = pg;
    ((float4v*)zbuf[0])[tid] = pz;
    if (tid < 64) hbuf[0][tid] = 0u;   // h0 = 0

    float hn = 0.0f;                    // this pair's h[j]
    const size_t obase = (size_t)(tid & 1) * ((size_t)NB * NT * NH)
                       + (size_t)b * NT * NH + j;
    __syncthreads();

    for (int t = 0; t < NT; ++t) {
        const int step = t & 15;
        const int cbuf = (t >> 4) & 1;

        // issue global prefetch of next 16-step chunk (regs, not LDS -> no
        // vmcnt drain at the per-step barrier)
        if (step == 0 && t + 16 < NT) {
            const int ci = (t >> 4) + 1;
            pg = gsrc4[ci * 256 + tid];
            pz = zsrc4[ci * 256 + tid];
        }

        // gate_h partial: 64 MACs as 32 v_dot2_f32_f16, h from LDS (2-way bcast b128)
        const half8* hs = (const half8*)&hbuf[t & 1][kh * 32];
        float acc = 0.0f;
        #pragma unroll
        for (int i = 0; i < 8; ++i) {
            half8 hv = hs[i];
            acc = fdot2f(w[4 * i + 0], __builtin_shufflevector(hv, hv, 0, 1), acc);
            acc = fdot2f(w[4 * i + 1], __builtin_shufflevector(hv, hv, 2, 3), acc);
            acc = fdot2f(w[4 * i + 2], __builtin_shufflevector(hv, hv, 4, 5), acc);
            acc = fdot2f(w[4 * i + 3], __builtin_shufflevector(hv, hv, 6, 7), acc);
        }
        const float gh = acc + __shfl_xor(acc, 1);

        // epilogue (both pair lanes redundantly)
        const float gx = (float)gbuf[cbuf][step][j];
        const float zv = (float)zbuf[cbuf][step][j];
        const float pre = gx + gh + bj;
        const float Kg = __builtin_amdgcn_rcpf(1.0f + __expf(-pre));
        hn = fast_tanh(hn + Kg * (zv - hn));

        // pack h_new pairs into next step's buffer (writers: tid%4==0)
        const float hn1 = __shfl_down(hn, 2);
        if ((tid & 3) == 0) {
            half2v hp = __builtin_amdgcn_cvt_pkrtz(hn, hn1);
            hbuf[(t + 1) & 1][j >> 1] = __builtin_bit_cast(unsigned int, hp);
        }

        // stage prefetched chunk into the other LDS buffer late in this chunk
        if (step == 14 && t + 2 < NT) {
            ((float4v*)gbuf[cbuf ^ 1])[tid] = pg;
            ((float4v*)zbuf[cbuf ^ 1])[tid] = pz;
        }

        // outputs: even lane -> copy0, odd lane -> copy1 (both hold hn[j]).
        // Safe in-place: overwrites staging only for t' = 2t-1024 (consumed).
        out[obase + (size_t)t * NH] = hn;

        __syncthreads();
    }
}

extern "C" void kernel_launch(void* const* d_in, const int* in_sizes, int n_in,
                              void* d_out, int out_size, void* d_ws, size_t ws_size,
                              hipStream_t stream) {
    (void)in_sizes; (void)n_in; (void)d_ws; (void)ws_size; (void)out_size;
    const float* x   = (const float*)d_in[0];
    const float* WxK = (const float*)d_in[1];
    const float* bxK = (const float*)d_in[2];
    const float* Wxz = (const float*)d_in[3];
    const float* bxz = (const float*)d_in[4];
    const float* Whk = (const float*)d_in[5];
    const float* bhk = (const float*)d_in[6];
    float* out = (float*)d_out;

    proj_kernel<<<4096, 256, 0, stream>>>(x, WxK, bxK, Wxz, bxz, (__fp16*)d_out);
    rnn_kernel<<<256, 256, 0, stream>>>(Whk, bhk, out);
}

// Round 3
// 605.029 us; speedup vs baseline: 1.2212x; 1.2212x over previous
//
#include <hip/hip_runtime.h>
#include <hip/hip_bf16.h>
#include <hip/hip_fp16.h>

#define NB 256      // batch
#define NT 1024     // time
#define ND 64       // input dim
#define NH 128      // hidden dim

typedef __fp16 half8 __attribute__((ext_vector_type(8)));
typedef __fp16 half2v __attribute__((ext_vector_type(2)));
typedef float float4v __attribute__((ext_vector_type(4)));

// fp16 staging inside d_out (fp16 element offsets):
//   gxK[b] at b*REGION_H + GX_OFF          (back half of out0's batch region)
//   z[b]   at Z_BASE + b*REGION_H + GX_OFF (back half of out1's batch region)
#define REGION_H 262144     // fp16 elems per batch region (= T*H floats)
#define GX_OFF   131072
#define Z_BASE   67108864   // out1 base in fp16 units (= B*T*H floats * 2 / 2... = B*T*H*2)

static __device__ __forceinline__ float fast_tanh(float v) {
    float e = __expf(2.0f * v);
    return 1.0f - 2.0f * __builtin_amdgcn_rcpf(e + 1.0f);
}

static __device__ __forceinline__ float fdot2f(half2v a, half2v b, float c) {
#if __has_builtin(__builtin_amdgcn_fdot2)
    return __builtin_amdgcn_fdot2(a, b, c, false);
#else
    return c + (float)a.x * (float)b.x + (float)a.y * (float)b.y;
#endif
}

// lgkm-only barrier: does NOT drain vmcnt (global stores keep flying)
static __device__ __forceinline__ void fast_barrier() {
    asm volatile("s_waitcnt lgkmcnt(0)\n\ts_barrier" ::: "memory");
}

static __device__ __forceinline__ float dpp_xor1_add(float x) {
#if __has_builtin(__builtin_amdgcn_mov_dpp)
    int o = __builtin_amdgcn_mov_dpp(__builtin_bit_cast(int, x), 0xB1, 0xF, 0xF, true);
    return x + __builtin_bit_cast(float, o);
#else
    return x + __shfl_xor(x, 1);
#endif
}

// ---------------- Phase 1: projections via f16 MFMA ----------------
// grid 1024 x 256 threads; each block: 256 rows of x in 4 subtiles of 64.
// W staged once per block; output repacked via LDS -> coalesced dwordx4 stores.
__global__ __launch_bounds__(256) void proj_kernel(
        const float* __restrict__ x,
        const float* __restrict__ WxK, const float* __restrict__ bxK,
        const float* __restrict__ Wxz, const float* __restrict__ bxz,
        __fp16* __restrict__ stg) {
    __shared__ __align__(16) __fp16 wsm[2][128][72];   // 36 KB
    __shared__ __align__(16) __fp16 xsm[64][72];       // 9 KB
    __shared__ __align__(16) __fp16 rpk[2][64][128];   // 32 KB repack (gx, z)

    const int tid = threadIdx.x;

    // stage W (both matrices) as fp16 into LDS, once
    for (int mat = 0; mat < 2; ++mat) {
        const float* Wsrc = mat ? Wxz : WxK;
        const float4v* ws4 = (const float4v*)(Wsrc + (size_t)(tid >> 1) * 64 + (tid & 1) * 32);
        #pragma unroll
        for (int i = 0; i < 4; ++i) {
            float4v a = ws4[2 * i], b = ws4[2 * i + 1];
            half8 hv = {(__fp16)a.x, (__fp16)a.y, (__fp16)a.z, (__fp16)a.w,
                        (__fp16)b.x, (__fp16)b.y, (__fp16)b.z, (__fp16)b.w};
            *(half8*)&wsm[mat][tid >> 1][(tid & 1) * 32 + i * 8] = hv;
        }
    }

    const int wid = tid >> 6, lane = tid & 63;
    const int l16 = lane & 15, kg = lane >> 4;

    float bKv[8], bzv[8];
    #pragma unroll
    for (int nt = 0; nt < 8; ++nt) {
        bKv[nt] = bxK[nt * 16 + l16];
        bzv[nt] = bxz[nt * 16 + l16];
    }

    for (int sub = 0; sub < 4; ++sub) {
        const int m0 = blockIdx.x * 256 + sub * 64;
        // stage x subtile as fp16
        {
            const float4v* xs4 = (const float4v*)(x + (size_t)(m0 + (tid >> 2)) * 64 + (tid & 3) * 16);
            #pragma unroll
            for (int i = 0; i < 2; ++i) {
                float4v a = xs4[2 * i], b = xs4[2 * i + 1];
                half8 hv = {(__fp16)a.x, (__fp16)a.y, (__fp16)a.z, (__fp16)a.w,
                            (__fp16)b.x, (__fp16)b.y, (__fp16)b.z, (__fp16)b.w};
                *(half8*)&xsm[tid >> 2][(tid & 3) * 16 + i * 8] = hv;
            }
        }
        __syncthreads();   // xsm+wsm ready; also separates prev store-phase rpk reads

        float4v acc[16] = {};   // [nt][mat]
        #pragma unroll
        for (int s = 0; s < 2; ++s) {
            half8 af = *(const half8*)&xsm[wid * 16 + l16][s * 32 + kg * 8];
            #pragma unroll
            for (int nt = 0; nt < 8; ++nt) {
                #pragma unroll
                for (int mat = 0; mat < 2; ++mat) {
                    half8 bf = *(const half8*)&wsm[mat][nt * 16 + l16][s * 32 + kg * 8];
                    acc[nt * 2 + mat] =
                        __builtin_amdgcn_mfma_f32_16x16x32_f16(af, bf, acc[nt * 2 + mat], 0, 0, 0);
                }
            }
        }

        // epilogue -> LDS repack. C/D layout: col = lane&15, row = (lane>>4)*4 + r
        #pragma unroll
        for (int nt = 0; nt < 8; ++nt) {
            const int col = nt * 16 + l16;
            #pragma unroll
            for (int r = 0; r < 4; ++r) {
                const int row = wid * 16 + kg * 4 + r;
                rpk[0][row][col] = (__fp16)(acc[nt * 2 + 0][r] + bKv[nt]);
                rpk[1][row][col] = (__fp16)fast_tanh(acc[nt * 2 + 1][r] + bzv[nt]);
            }
        }
        __syncthreads();   // rpk ready

        // wide coalesced stores: 64x128 fp16 tile is CONTIGUOUS in global
        const int bb = m0 >> 10, tt0 = m0 & 1023;
        const size_t g0 = (size_t)bb * REGION_H + GX_OFF + (size_t)tt0 * NH;
        float4v* dstg = (float4v*)(stg + g0);
        float4v* dstz = (float4v*)(stg + g0 + (size_t)Z_BASE);
        const float4v* srcg = (const float4v*)rpk[0];
        const float4v* srcz = (const float4v*)rpk[1];
        #pragma unroll
        for (int i = 0; i < 4; ++i) {
            dstg[tid * 4 + i] = srcg[tid * 4 + i];
            dstz[tid * 4 + i] = srcz[tid * 4 + i];
        }
    }
}

// ---------------- Phase 2: sequential recurrence ----------------
// grid 256 (block = batch) x 256 threads. thread: j = tid>>1, kh = tid&1.
__global__ __launch_bounds__(256) void rnn_kernel(
        const float* __restrict__ Whk, const float* __restrict__ bhk,
        float* __restrict__ out) {
    __shared__ __align__(16) __fp16 hbuf[2][128];        // h as fp16, dbuf per step
    __shared__ __align__(16) __fp16 gbuf[2][16][128];    // gxK chunk dbuf
    __shared__ __align__(16) __fp16 zbuf[2][16][128];    // z   chunk dbuf

    const int tid = threadIdx.x;
    const int b = blockIdx.x;
    const int j = tid >> 1, kh = tid & 1;

    // W_hK row j, k-half kh, packed fp16 in 32 VGPRs
    half2v w[32];
    {
        const float4v* wsrc = (const float4v*)(Whk + (size_t)j * NH + kh * 64);
        #pragma unroll
        for (int i = 0; i < 16; ++i) {
            float4v wv = wsrc[i];
            w[2 * i]     = __builtin_amdgcn_cvt_pkrtz(wv.x, wv.y);
            w[2 * i + 1] = __builtin_amdgcn_cvt_pkrtz(wv.z, wv.w);
        }
    }
    const float bj = bhk[j];

    const __fp16* gxb = (const __fp16*)out + (size_t)b * REGION_H + GX_OFF;
    const float4v* gsrc4 = (const float4v*)gxb;
    const float4v* zsrc4 = (const float4v*)(gxb + (size_t)Z_BASE);

    // preload chunk 0 straight into LDS buf0
    float4v pg = gsrc4[tid];
    float4v pz = zsrc4[tid];
    ((float4v*)gbuf[0])[tid] = pg;
    ((float4v*)zbuf[0])[tid] = pz;
    if (tid < 128) hbuf[0][tid] = (__fp16)0.0f;   // h0 = 0

    float hn = 0.0f;
    float oreg[16];
    const size_t obase = (size_t)kh * ((size_t)NB * NT * NH)
                       + (size_t)b * NT * NH + j;
    __syncthreads();

    for (int c = 0; c < 64; ++c) {
        const int cb = c & 1;

        // issue global prefetch of next chunk (into regs; no LDS dependency)
        if (c + 1 < 64) {
            pg = gsrc4[(c + 1) * 256 + tid];
            pz = zsrc4[(c + 1) * 256 + tid];
        }

        // per-chunk gx/z for this thread's j -> registers (off critical path)
        float gxv[16], zvv[16];
        #pragma unroll
        for (int s = 0; s < 16; ++s) {
            gxv[s] = (float)gbuf[cb][s][j] + bj;
            zvv[s] = (float)zbuf[cb][s][j];
        }

        #pragma unroll
        for (int s = 0; s < 16; ++s) {
            const int t = c * 16 + s;
            const half8* hs = (const half8*)&hbuf[t & 1][kh * 64];
            float a0 = 0.f, a1 = 0.f, a2 = 0.f, a3 = 0.f;
            #pragma unroll
            for (int i = 0; i < 8; ++i) {
                half8 hv = hs[i];
                a0 = fdot2f(w[4 * i + 0], __builtin_shufflevector(hv, hv, 0, 1), a0);
                a1 = fdot2f(w[4 * i + 1], __builtin_shufflevector(hv, hv, 2, 3), a1);
                a2 = fdot2f(w[4 * i + 2], __builtin_shufflevector(hv, hv, 4, 5), a2);
                a3 = fdot2f(w[4 * i + 3], __builtin_shufflevector(hv, hv, 6, 7), a3);
            }
            const float acc = (a0 + a1) + (a2 + a3);
            const float gh = dpp_xor1_add(acc);          // pair k-halves via DPP

            const float d = zvv[s] - hn;                 // off-chain vs gh
            const float pre = gh + gxv[s];
            const float Kg = __builtin_amdgcn_rcpf(1.0f + __expf(-pre));
            const float v = __builtin_fmaf(Kg, d, hn);
            hn = fast_tanh(v);
            oreg[s] = hn;

            if (kh == 0) hbuf[(t + 1) & 1][j] = (__fp16)hn;

            if (s == 14 && c + 1 < 64) {                 // stage prefetched chunk
                ((float4v*)gbuf[cb ^ 1])[tid] = pg;
                ((float4v*)zbuf[cb ^ 1])[tid] = pz;
            }
            fast_barrier();                              // lgkm-only, no vmcnt drain
        }

        // flush 16 outputs (coalesced per t); drains in background
        #pragma unroll
        for (int s = 0; s < 16; ++s)
            out[obase + (size_t)(c * 16 + s) * NH] = oreg[s];
    }
}

extern "C" void kernel_launch(void* const* d_in, const int* in_sizes, int n_in,
                              void* d_out, int out_size, void* d_ws, size_t ws_size,
                              hipStream_t stream) {
    (void)in_sizes; (void)n_in; (void)d_ws; (void)ws_size; (void)out_size;
    const float* x   = (const float*)d_in[0];
    const float* WxK = (const float*)d_in[1];
    const float* bxK = (const float*)d_in[2];
    const float* Wxz = (const float*)d_in[3];
    const float* bxz = (const float*)d_in[4];
    const float* Whk = (const float*)d_in[5];
    const float* bhk = (const float*)d_in[6];
    float* out = (float*)d_out;

    proj_kernel<<<1024, 256, 0, stream>>>(x, WxK, bxK, Wxz, bxz, (__fp16*)d_out);
    rnn_kernel<<<256, 256, 0, stream>>>(Whk, bhk, out);
}